// Round 4
// baseline (479.958 us; speedup 1.0000x reference)
//
#include <hip/hip_runtime.h>
#include <hip/hip_fp16.h>
#include <hip/hip_cooperative_groups.h>
#include <stdint.h>

namespace cg = cooperative_groups;

#define BATCH 4096
#define N_IN  512
#define H1    1536
#define H2    1536
#define N_OUT 512
#define FAN   32
#define E0 (H1 * FAN)
#define E1 (H2 * FAN)
#define E2 (N_OUT * FAN)
#define ETOT (E0 + E1 + E2)
#define NNODES (H1 + H2 + N_OUT)   // 3584 non-input nodes
#define MAXDEG 128                 // slot capacity; Poisson(32) max ~54, 128 = guard-free staging

#define NBLK   512                 // cooperative grid: 2 blocks/CU, co-resident by construction
#define NTHR   256                 // 4 waves/block -> 8 waves/CU
#define GSTRIDE (NBLK * NTHR)

// ---- workspace layout (bytes), total 37,238,784 (< 38.7 MB proven safe) ----
// nv    : 4096 rows x 4096 cols x 2B (fp16) = 33,554,432
//         rows 0..511 = x^T, 512..2047 = h1, 2048..3583 = h2, 3584..4095 = out^T
// edges : slotted [NNODES][MAXDEG] int2 = 3,670,016
// cnt   : NNODES ints = 14,336
#define OFF_EDGES 33554432
#define OFF_CNT   (OFF_EDGES + NNODES * MAXDEG * 8)

// ---------------- level body: wave = one node, fixed col-tile per block -------------
// Block b permanently owns col-tile (b & 7) across ALL levels: the h-columns it
// writes at level k are exactly the columns it gathers at level k+1, so panel
// locality in its XCD's L2 holds by construction (no blockIdx->XCD mapping
// assumption). Inner loop = proven R2 uint4 gather (16B/lane, readlane-scalarized
// edge broadcast); R1/R2/R3 established it is insensitive to ILP depth, wave
// count, and footprint, so it is carried unchanged.
__device__ __forceinline__ void level_body(const int2* __restrict__ edges,   // level base
                                           const int* __restrict__ cnt,      // level base
                                           const uint4* __restrict__ nv,
                                           uint4* __restrict__ outb,         // level out base
                                           const int H, const int b, const int tid) {
    const int lane = tid & 63;
    const int wv   = tid >> 6;
    const int col8 = ((b & 7) << 6) | lane;     // uint4 index in row, 0..511
    const int slot = ((b >> 3) << 2) | wv;      // 0..255: node slot per sweep

    for (int n0 = 0; n0 < H; n0 += 256) {
        const int node = __builtin_amdgcn_readfirstlane(n0 + slot);
        int c = cnt[node];
        c = (c < 0) ? 0 : (c > MAXDEG ? MAXDEG : c);

        float a0 = 0.f, a1 = 0.f, a2 = 0.f, a3 = 0.f, a4 = 0.f, a5 = 0.f, a6 = 0.f, a7 = 0.f;

#define ACC8(q, W) {                                                    \
    const __half2 h0 = *(const __half2*)&(q).x;                         \
    const __half2 h1 = *(const __half2*)&(q).y;                         \
    const __half2 h2 = *(const __half2*)&(q).z;                         \
    const __half2 h3 = *(const __half2*)&(q).w;                         \
    a0 = fmaf(__low2float(h0),  (W), a0);                               \
    a1 = fmaf(__high2float(h0), (W), a1);                               \
    a2 = fmaf(__low2float(h1),  (W), a2);                               \
    a3 = fmaf(__high2float(h1), (W), a3);                               \
    a4 = fmaf(__low2float(h2),  (W), a4);                               \
    a5 = fmaf(__high2float(h2), (W), a5);                               \
    a6 = fmaf(__low2float(h3),  (W), a6);                               \
    a7 = fmaf(__high2float(h3), (W), a7); }

        for (int base = 0; base < c; base += 64) {
            const int2 my = edges[(size_t)node * MAXDEG + base + lane];
            const int m = (c - base < 64) ? (c - base) : 64;
            int j = 0;
            for (; j + 4 <= m; j += 4) {
                const int   s0i = __builtin_amdgcn_readlane(my.x, j)     & 4095;
                const int   s1i = __builtin_amdgcn_readlane(my.x, j + 1) & 4095;
                const int   s2i = __builtin_amdgcn_readlane(my.x, j + 2) & 4095;
                const int   s3i = __builtin_amdgcn_readlane(my.x, j + 3) & 4095;
                const float wa  = __int_as_float(__builtin_amdgcn_readlane(my.y, j));
                const float wb  = __int_as_float(__builtin_amdgcn_readlane(my.y, j + 1));
                const float wc  = __int_as_float(__builtin_amdgcn_readlane(my.y, j + 2));
                const float wd  = __int_as_float(__builtin_amdgcn_readlane(my.y, j + 3));
                const uint4 q0 = nv[((size_t)s0i << 9) | col8];
                const uint4 q1 = nv[((size_t)s1i << 9) | col8];
                const uint4 q2 = nv[((size_t)s2i << 9) | col8];
                const uint4 q3 = nv[((size_t)s3i << 9) | col8];
                ACC8(q0, wa);
                ACC8(q1, wb);
                ACC8(q2, wc);
                ACC8(q3, wd);
            }
            for (; j < m; ++j) {
                const int   s0i = __builtin_amdgcn_readlane(my.x, j) & 4095;
                const float wa  = __int_as_float(__builtin_amdgcn_readlane(my.y, j));
                const uint4 q0 = nv[((size_t)s0i << 9) | col8];
                ACC8(q0, wa);
            }
        }
#undef ACC8

        a0 = fmaxf(a0, 0.f); a1 = fmaxf(a1, 0.f); a2 = fmaxf(a2, 0.f); a3 = fmaxf(a3, 0.f);
        a4 = fmaxf(a4, 0.f); a5 = fmaxf(a5, 0.f); a6 = fmaxf(a6, 0.f); a7 = fmaxf(a7, 0.f);

        const __half2 h0 = __floats2half2_rn(a0, a1);
        const __half2 h1 = __floats2half2_rn(a2, a3);
        const __half2 h2 = __floats2half2_rn(a4, a5);
        const __half2 h3 = __floats2half2_rn(a6, a7);
        uint4 p;
        p.x = *(const uint32_t*)&h0; p.y = *(const uint32_t*)&h1;
        p.z = *(const uint32_t*)&h2; p.w = *(const uint32_t*)&h3;
        outb[((size_t)node << 9) | col8] = p;
    }
}

// ---------------- single fused cooperative kernel: all 8 phases -------------------
// Phases: 0 zero-cnt | 1 edge-fill + x-transpose (independent, no sync between) |
// 2/3/4 levels | 5 out-transpose. grid.sync() (device-scope fence) between
// dependent phases gives cross-XCD visibility of h-panels and edge tables.
__global__ __launch_bounds__(NTHR, 8)
void k_mega(const float* __restrict__ x,
            const int* __restrict__ s0, const int* __restrict__ d0, const float* __restrict__ w0,
            const int* __restrict__ s1, const int* __restrict__ d1, const float* __restrict__ w1,
            const int* __restrict__ s2, const int* __restrict__ d2, const float* __restrict__ w2,
            uint4* __restrict__ nv4, int2* __restrict__ edges, int* __restrict__ cnt,
            float* __restrict__ out) {
    cg::grid_group grid = cg::this_grid();
    const int tid = threadIdx.x;
    const int b   = blockIdx.x;

    __shared__ float tile[32][33];

    // ---- phase 0: zero edge counters ----
    for (int i = b * NTHR + tid; i < NNODES; i += GSTRIDE) cnt[i] = 0;
    grid.sync();

    // ---- phase 1: slotted edge fill (grid-stride) ----
    for (int e = b * NTHR + tid; e < ETOT; e += GSTRIDE) {
        int src, node; float w;
        if (e < E0)           { src = s0[e];          node = d0[e];              w = w0[e]; }
        else if (e < E0 + E1) { int i = e - E0;       src = s1[i]; node = H1 + d1[i];      w = w1[i]; }
        else                  { int i = e - E0 - E1;  src = s2[i]; node = H1 + H2 + d2[i]; w = w2[i]; }
        const int pos = atomicAdd(&cnt[node], 1);
        if (pos < MAXDEG) edges[node * MAXDEG + pos] = make_int2(src, __float_as_int(w));
    }

    // ---- phase 1b: x [B,N_IN] fp32 -> nv rows 0..511 fp16 (4 tiles/block) ----
    {
        __half* xT = (__half*)nv4;
        const int tx = tid & 31, ty = tid >> 5;   // 32 x 8
        for (int i = 0; i < 4; ++i) {
            const int t  = b * 4 + i;             // 2048 tiles = 16 x 128
            const int n0 = (t & 15) << 5;
            const int b0 = (t >> 4) << 5;
            __syncthreads();
#pragma unroll
            for (int k = 0; k < 32; k += 8)
                tile[ty + k][tx] = x[(size_t)(b0 + ty + k) * N_IN + (n0 + tx)];
            __syncthreads();
#pragma unroll
            for (int k = 0; k < 32; k += 8)
                xT[(size_t)(n0 + ty + k) * BATCH + (b0 + tx)] = __float2half_rn(tile[tx][ty + k]);
        }
    }
    grid.sync();

    // ---- phases 2/3/4: the three levels ----
    level_body(edges, cnt, nv4,
               nv4 + (size_t)N_IN * 512, H1, b, tid);
    grid.sync();
    level_body(edges + (size_t)H1 * MAXDEG, cnt + H1, nv4,
               nv4 + (size_t)(N_IN + H1) * 512, H2, b, tid);
    grid.sync();
    level_body(edges + (size_t)(H1 + H2) * MAXDEG, cnt + H1 + H2, nv4,
               nv4 + (size_t)(N_IN + H1 + H2) * 512, N_OUT, b, tid);
    grid.sync();

    // ---- phase 5: out^T rows fp16 -> d_out [B, N_OUT] fp32 (4 tiles/block) ----
    {
        const __half* outh = (const __half*)(nv4 + (size_t)(N_IN + H1 + H2) * 512);
        const int tx = tid & 31, ty = tid >> 5;
        for (int i = 0; i < 4; ++i) {
            const int t  = b * 4 + i;             // 2048 tiles = 16 x 128
            const int n0 = (t & 15) << 5;
            const int b0 = (t >> 4) << 5;
            __syncthreads();
#pragma unroll
            for (int k = 0; k < 32; k += 8)
                tile[ty + k][tx] = __half2float(outh[(size_t)(n0 + ty + k) * BATCH + (b0 + tx)]);
            __syncthreads();
#pragma unroll
            for (int k = 0; k < 32; k += 8)
                out[(size_t)(b0 + ty + k) * N_OUT + (n0 + tx)] = tile[tx][ty + k];
        }
    }
}

extern "C" void kernel_launch(void* const* d_in, const int* in_sizes, int n_in,
                              void* d_out, int out_size, void* d_ws, size_t ws_size,
                              hipStream_t stream) {
    const float* x  = (const float*)d_in[0];
    const int* s0   = (const int*)d_in[1];
    const int* dd0  = (const int*)d_in[2];
    const float* w0 = (const float*)d_in[3];
    const int* s1   = (const int*)d_in[4];
    const int* dd1  = (const int*)d_in[5];
    const float* w1 = (const float*)d_in[6];
    const int* s2   = (const int*)d_in[7];
    const int* dd2  = (const int*)d_in[8];
    const float* w2 = (const float*)d_in[9];

    char* ws        = (char*)d_ws;
    uint4*    nv4   = (uint4*)ws;                    // fp16 node rows, 512 uint4/row
    int2*     edges = (int2*)(ws + OFF_EDGES);
    int*      cnt   = (int*)(ws + OFF_CNT);
    float*    outp  = (float*)d_out;

    void* args[] = { (void*)&x,
                     (void*)&s0, (void*)&dd0, (void*)&w0,
                     (void*)&s1, (void*)&dd1, (void*)&w1,
                     (void*)&s2, (void*)&dd2, (void*)&w2,
                     (void*)&nv4, (void*)&edges, (void*)&cnt,
                     (void*)&outp };
    hipLaunchCooperativeKernel((const void*)k_mega, dim3(NBLK), dim3(NTHR),
                               args, 0, stream);
}

// Round 5
// 145.549 us; speedup vs baseline: 3.2976x; 3.2976x over previous
//
#include <hip/hip_runtime.h>
#include <hip/hip_fp16.h>
#include <stdint.h>

#define BATCH 4096
#define N_IN  512
#define H1    1536
#define H2    1536
#define N_OUT 512
#define FAN   32
#define E0 (H1 * FAN)
#define E1 (H2 * FAN)
#define E2 (N_OUT * FAN)
#define ETOT (E0 + E1 + E2)
#define NNODES (H1 + H2 + N_OUT)   // 3584 non-input nodes
#define MAXDEG 128                 // slot capacity; Poisson(32) max ~54, 128 = guard-free staging

// ---- anti-aliasing row pad ----
// R4 counters proved the levels are pure-latency-bound (VALUBusy 7.5%, HBM 2.5%,
// time ~ 1/waves). Root cause theory: 8192 B (2^13) row stride aliases both L1
// sets (bits [12:6] constant across rows) and L2 sets (64*s mod 2048 -> 32
// set-groups for 2048 rows => 512 KB effective L2, panel thrashes to L3).
// Fix: row stride 520 uint4 = 8320 B = 65 x 128 B lines; 65 is coprime with the
// L2 set count -> full set coverage, L1 likewise de-aliased. Only the stride
// changes vs the 147.6 us R2 base.
#define ROWU4 520                  // uint4 per nv row (512 data + 8 pad)
#define ROWH  (ROWU4 * 8)          // halfs per nv row = 4160

// ---- workspace layout (bytes), total 37,763,072 (< 38.7 MB proven safe) ----
// nv    : 4096 rows x 8320 B = 34,078,720
//         rows 0..511 = x^T, 512..2047 = h1, 2048..3583 = h2, 3584..4095 = out^T
// edges : slotted [NNODES][MAXDEG] int2 = 3,670,016
// cnt   : NNODES ints = 14,336
#define OFF_EDGES 34078720
#define OFF_CNT   (OFF_EDGES + NNODES * MAXDEG * 8)

// ---------- x [B, N_IN] fp32 -> rows 0..511 of nv (fp16, [node][batch], padded) ----------
__global__ __launch_bounds__(256) void k_transpose_in(const float* __restrict__ x,
                                                      __half* __restrict__ xT) {
    __shared__ float tile[32][33];
    const int tx = threadIdx.x, ty = threadIdx.y;   // 32 x 8
    const int n0 = blockIdx.x * 32;                 // node base
    const int b0 = blockIdx.y * 32;                 // batch base
#pragma unroll
    for (int k = 0; k < 32; k += 8)
        tile[ty + k][tx] = x[(size_t)(b0 + ty + k) * N_IN + (n0 + tx)];
    __syncthreads();
#pragma unroll
    for (int k = 0; k < 32; k += 8)
        xT[(size_t)(n0 + ty + k) * ROWH + (b0 + tx)] = __float2half_rn(tile[tx][ty + k]);
}

// ---------- slotted edge-table fill: one pass, no scan ----------
__global__ __launch_bounds__(256) void k_fill(const int* __restrict__ s0, const int* __restrict__ d0, const float* __restrict__ w0,
                                              const int* __restrict__ s1, const int* __restrict__ d1, const float* __restrict__ w1,
                                              const int* __restrict__ s2, const int* __restrict__ d2, const float* __restrict__ w2,
                                              int* __restrict__ cnt, int2* __restrict__ edges) {
    const int e = blockIdx.x * 256 + threadIdx.x;
    int src, node; float w;
    if (e < E0)           { src = s0[e];          node = d0[e];                w = w0[e]; }
    else if (e < E0 + E1) { int i = e - E0;       src = s1[i]; node = H1 + d1[i];        w = w1[i]; }
    else                  { int i = e - E0 - E1;  src = s2[i]; node = H1 + H2 + d2[i];   w = w2[i]; }
    const int pos = atomicAdd(&cnt[node], 1);
    if (pos < MAXDEG) edges[node * MAXDEG + pos] = make_int2(src, __float_as_int(w));
}

// ---------- level kernel: 256 thr = 4 waves, wave = one node, 8 col-tiles ----------
// Identical to the 147.6 us R2 base except nv rows are ROWU4-strided (de-aliased).
__global__ __launch_bounds__(256, 8)
void k_level(const int2* __restrict__ edges,   // pre-offset: level base * MAXDEG
             const int* __restrict__ cnt,      // pre-offset: level node base
             const uint4* __restrict__ nv,     // ROWU4 uint4 per node row (fp16 x8)
             uint4* __restrict__ outb) {       // pre-offset row base (uint4 units)
    const int lane = threadIdx.x & 63;
    const int wv   = threadIdx.x >> 6;
    // wave-uniform node id hoisted to SGPR: scalar edge/cnt addressing
    const int node = __builtin_amdgcn_readfirstlane((blockIdx.y << 2) | wv);
    const int col8 = (blockIdx.x << 6) | lane;  // uint4 index in row, 0..511

    int c = cnt[node];
    c = (c < 0) ? 0 : (c > MAXDEG ? MAXDEG : c);

    float a0 = 0.f, a1 = 0.f, a2 = 0.f, a3 = 0.f, a4 = 0.f, a5 = 0.f, a6 = 0.f, a7 = 0.f;

#define ACC8(q, W) {                                                    \
    const __half2 h0 = *(const __half2*)&(q).x;                         \
    const __half2 h1 = *(const __half2*)&(q).y;                         \
    const __half2 h2 = *(const __half2*)&(q).z;                         \
    const __half2 h3 = *(const __half2*)&(q).w;                         \
    a0 = fmaf(__low2float(h0),  (W), a0);                               \
    a1 = fmaf(__high2float(h0), (W), a1);                               \
    a2 = fmaf(__low2float(h1),  (W), a2);                               \
    a3 = fmaf(__high2float(h1), (W), a3);                               \
    a4 = fmaf(__low2float(h2),  (W), a4);                               \
    a5 = fmaf(__high2float(h2), (W), a5);                               \
    a6 = fmaf(__low2float(h3),  (W), a6);                               \
    a7 = fmaf(__high2float(h3), (W), a7); }

    for (int base = 0; base < c; base += 64) {
        // stage up to 64 edges of this wave's node into registers (always in-bounds)
        const int2 my = edges[(size_t)node * MAXDEG + base + lane];
        const int m = (c - base < 64) ? (c - base) : 64;
        int j = 0;
        for (; j + 4 <= m; j += 4) {
            const int   s0i = __builtin_amdgcn_readlane(my.x, j)     & 4095;
            const int   s1i = __builtin_amdgcn_readlane(my.x, j + 1) & 4095;
            const int   s2i = __builtin_amdgcn_readlane(my.x, j + 2) & 4095;
            const int   s3i = __builtin_amdgcn_readlane(my.x, j + 3) & 4095;
            const float wa  = __int_as_float(__builtin_amdgcn_readlane(my.y, j));
            const float wb  = __int_as_float(__builtin_amdgcn_readlane(my.y, j + 1));
            const float wc  = __int_as_float(__builtin_amdgcn_readlane(my.y, j + 2));
            const float wd  = __int_as_float(__builtin_amdgcn_readlane(my.y, j + 3));
            const uint4 q0 = nv[(size_t)s0i * ROWU4 + col8];
            const uint4 q1 = nv[(size_t)s1i * ROWU4 + col8];
            const uint4 q2 = nv[(size_t)s2i * ROWU4 + col8];
            const uint4 q3 = nv[(size_t)s3i * ROWU4 + col8];
            ACC8(q0, wa);
            ACC8(q1, wb);
            ACC8(q2, wc);
            ACC8(q3, wd);
        }
        for (; j < m; ++j) {
            const int   s0i = __builtin_amdgcn_readlane(my.x, j) & 4095;
            const float wa  = __int_as_float(__builtin_amdgcn_readlane(my.y, j));
            const uint4 q0 = nv[(size_t)s0i * ROWU4 + col8];
            ACC8(q0, wa);
        }
    }
#undef ACC8

    a0 = fmaxf(a0, 0.f); a1 = fmaxf(a1, 0.f); a2 = fmaxf(a2, 0.f); a3 = fmaxf(a3, 0.f);
    a4 = fmaxf(a4, 0.f); a5 = fmaxf(a5, 0.f); a6 = fmaxf(a6, 0.f); a7 = fmaxf(a7, 0.f);

    const __half2 h0 = __floats2half2_rn(a0, a1);
    const __half2 h1 = __floats2half2_rn(a2, a3);
    const __half2 h2 = __floats2half2_rn(a4, a5);
    const __half2 h3 = __floats2half2_rn(a6, a7);
    uint4 p;
    p.x = *(const uint32_t*)&h0; p.y = *(const uint32_t*)&h1;
    p.z = *(const uint32_t*)&h2; p.w = *(const uint32_t*)&h3;
    outb[(size_t)node * ROWU4 + col8] = p;
}

// ---------- out^T rows (fp16, padded [N_OUT][ROWH]) -> d_out [B, N_OUT] fp32 ----------
__global__ __launch_bounds__(256) void k_transpose_out(const __half* __restrict__ outh,
                                                       float* __restrict__ out) {
    __shared__ float tile[32][33];
    const int tx = threadIdx.x, ty = threadIdx.y;   // 32 x 8
    const int n0 = blockIdx.x * 32;
    const int b0 = blockIdx.y * 32;
#pragma unroll
    for (int k = 0; k < 32; k += 8)
        tile[ty + k][tx] = __half2float(outh[(size_t)(n0 + ty + k) * ROWH + (b0 + tx)]);
    __syncthreads();
#pragma unroll
    for (int k = 0; k < 32; k += 8)
        out[(size_t)(b0 + ty + k) * N_OUT + (n0 + tx)] = tile[tx][ty + k];
}

extern "C" void kernel_launch(void* const* d_in, const int* in_sizes, int n_in,
                              void* d_out, int out_size, void* d_ws, size_t ws_size,
                              hipStream_t stream) {
    const float* x  = (const float*)d_in[0];
    const int* s0   = (const int*)d_in[1];
    const int* dd0  = (const int*)d_in[2];
    const float* w0 = (const float*)d_in[3];
    const int* s1   = (const int*)d_in[4];
    const int* dd1  = (const int*)d_in[5];
    const float* w1 = (const float*)d_in[6];
    const int* s2   = (const int*)d_in[7];
    const int* dd2  = (const int*)d_in[8];
    const float* w2 = (const float*)d_in[9];

    char* ws        = (char*)d_ws;
    uint4*    nv4   = (uint4*)ws;                    // fp16 node rows, ROWU4 uint4/row
    int2*     edges = (int2*)(ws + OFF_EDGES);
    int*      cnt   = (int*)(ws + OFF_CNT);

    // slotted edge build: memset + one massively-parallel fill (no scan)
    hipMemsetAsync(cnt, 0, NNODES * sizeof(int), stream);
    k_fill<<<ETOT / 256, 256, 0, stream>>>(s0, dd0, w0, s1, dd1, w1, s2, dd2, w2, cnt, edges);

    // x -> fp16 transposed node-value rows 0..511
    k_transpose_in<<<dim3(N_IN / 32, BATCH / 32), dim3(32, 8), 0, stream>>>(x, (__half*)ws);

    // levels: grid (8 col-tiles, H/4), 256 threads = 4 waves = 4 nodes
    k_level<<<dim3(8, H1 / 4), 256, 0, stream>>>(edges, cnt, nv4,
                                                 nv4 + (size_t)N_IN * ROWU4);
    k_level<<<dim3(8, H2 / 4), 256, 0, stream>>>(edges + (size_t)H1 * MAXDEG, cnt + H1, nv4,
                                                 nv4 + (size_t)(N_IN + H1) * ROWU4);
    k_level<<<dim3(8, N_OUT / 4), 256, 0, stream>>>(edges + (size_t)(H1 + H2) * MAXDEG, cnt + H1 + H2, nv4,
                                                    nv4 + (size_t)(N_IN + H1 + H2) * ROWU4);

    // out^T (fp16) -> d_out [B, N_OUT] fp32
    k_transpose_out<<<dim3(N_OUT / 32, BATCH / 32), dim3(32, 8), 0, stream>>>(
        (const __half*)(ws + (size_t)(N_IN + H1 + H2) * ROWH * 2), (float*)d_out);
}